// Round 1
// 59.239 us; speedup vs baseline: 1.0405x; 1.0405x over previous
//
#include <hip/hip_runtime.h>

#define HOP 160
#define FFT 1024
#define PAD (FFT / 2)
#define NUM_LABELS 72
#define BATCH 4
#define T 240000
#define NOUT 1501              // (T + 2*PAD - FFT)/HOP + 1
#define WPB 4                  // waves per block
#define NSUB 4                 // sub-hists per wave (lane>>4) to cut atomic serialization
#define HSTRIDE 72             // sub-hist stride in ints

// One wave per (batch, window). 6004 waves total = 1501 blocks x 4 waves exactly
// (no tail -> uniform barrier counts). Each wave:
//   - 4 coalesced int4 loads cover the 1024-label window (start is 16B-aligned:
//     s = 160*w - 512, s % 4 == 0)
//   - 16 LDS atomicAdds into 4 per-16-lane sub-histograms (4x fewer same-address
//     collisions than a single per-wave hist)
//   - merge + 64-lane shuffle-butterfly argmax on packed keys (count<<7 | 71-label)
//     so the max matches jnp.argmax lowest-index tiebreak.
// Replaces the old 8-window serial sliding loop (3 blocks/CU, 24 barrier phases,
// 4% VALUBusy) with 23 independent waves/CU; redundant window re-reads are
// L2-resident and free.
__global__ __launch_bounds__(256) void label_window_argmax(
    const int* __restrict__ lbl, int* __restrict__ out)
{
    __shared__ int hist[WPB][NSUB][HSTRIDE];

    const int tid  = threadIdx.x;
    const int wave = tid >> 6;
    const int lane = tid & 63;
    const int sub  = lane >> 4;

    // zero this wave's sub-hists: 288 ints / 64 lanes
    int* hbase = &hist[wave][0][0];
    for (int i = lane; i < NSUB * HSTRIDE; i += 64)
        hbase[i] = 0;

    const int gid = blockIdx.x * WPB + wave;     // 0..6003
    const int b   = gid / NOUT;
    const int w   = gid - b * NOUT;
    const int* __restrict__ row = lbl + b * T;
    const int s = w * HOP - PAD;

    __syncthreads();                              // zeros visible

    int* hsub = &hist[wave][sub][0];
    if (s >= 0 && s + FFT <= T) {
        // fast path (1493/1501 windows): no reflection
        const int4* p = reinterpret_cast<const int4*>(row + s);
#pragma unroll
        for (int k = 0; k < 4; ++k) {
            const int4 v = p[k * 64 + lane];      // 1 KiB/instr, coalesced
            atomicAdd(&hsub[v.x], 1);
            atomicAdd(&hsub[v.y], 1);
            atomicAdd(&hsub[v.z], 1);
            atomicAdd(&hsub[v.w], 1);
        }
    } else {
        // boundary windows: reflect-pad indexing, scalar
        auto refl = [&](int j) {
            j = (j < 0) ? -j : j;                 // left reflect (no edge repeat)
            j = (j >= T) ? (2 * (T - 1) - j) : j; // right reflect
            return j;
        };
#pragma unroll
        for (int k = 0; k < 16; ++k) {
            const int lab = row[refl(s + k * 64 + lane)];
            atomicAdd(&hsub[lab], 1);
        }
    }

    __syncthreads();                              // all atomics done

    // counts: label = lane (0..63) for all lanes; labels 64..71 on lanes 0..7
    int k0;
    {
        const int c0 = hist[wave][0][lane] + hist[wave][1][lane]
                     + hist[wave][2][lane] + hist[wave][3][lane];
        k0 = (c0 << 7) | (NUM_LABELS - 1 - lane);
    }
    int k1 = 0;                                   // cnt=0,lab=71 -> key 0, never wins
    if (lane < NUM_LABELS - 64) {
        const int l2 = 64 + lane;
        const int c1 = hist[wave][0][l2] + hist[wave][1][l2]
                     + hist[wave][2][l2] + hist[wave][3][l2];
        k1 = (c1 << 7) | (NUM_LABELS - 1 - l2);
    }
    int k = max(k0, k1);
#pragma unroll
    for (int off = 32; off; off >>= 1)
        k = max(k, __shfl_xor(k, off, 64));
    if (lane == 0)
        out[b * NOUT + w] = NUM_LABELS - 1 - (k & 127);
}

extern "C" void kernel_launch(void* const* d_in, const int* in_sizes, int n_in,
                              void* d_out, int out_size, void* d_ws, size_t ws_size,
                              hipStream_t stream) {
    const int* lbl = (const int*)d_in[0];
    // d_in[1] is the frozen all-ones conv weight: conv == windowed count, ignore.
    int* out = (int*)d_out;

    static_assert(WPB * ((BATCH * NOUT) / WPB) == BATCH * NOUT, "exact wave tiling");
    dim3 grid((BATCH * NOUT) / WPB);              // 1501 blocks, 4 waves each
    label_window_argmax<<<grid, 256, 0, stream>>>(lbl, out);
}

// Round 2
// 58.617 us; speedup vs baseline: 1.0515x; 1.0106x over previous
//
#include <hip/hip_runtime.h>

#define HOP 160
#define FFT 1024
#define PAD (FFT / 2)
#define NUM_LABELS 72
#define BATCH 4
#define T 240000
#define NOUT 1501              // (T + 2*PAD - FFT)/HOP + 1
#define WPB 4                  // waves per block
#define NSUB 8                 // sub-hists per wave (8 lanes each) -> ~no same-addr serialization
#define HSTRIDE 72             // sub-hist stride in ints (stride-72 rows: merge reads are 2-way/free)

// One wave per (batch, window). 6004 waves = 1501 blocks x 4 waves exactly.
// hist[wave] is WAVE-PRIVATE -> no block barriers at all; per-wave DS-pipe
// ordering + s_waitcnt lgkmcnt(0) is sufficient. Each wave:
//   - 4 coalesced int4 loads cover the 1024-label window (start 16B-aligned:
//     s = 160*w - 512, s % 4 == 0)
//   - 16 ds_atomic_add into 8 per-8-lane sub-histograms (same-address collision
//     ~1.1-way vs 2-3-way at 4 subs)
//   - merge (8 stride-72 ds_reads, lane-distinct banks) + 64-lane shuffle
//     butterfly on packed keys (count<<7 | 71-label) == jnp.argmax low-index tiebreak.
// Harness floor note: timed graph contains a 256 MiB poison fill (~40.5 us @83%
// HBM peak); kernel term is the only controllable part.
__global__ __launch_bounds__(256) void label_window_argmax(
    const int* __restrict__ lbl, int* __restrict__ out)
{
    __shared__ int hist[WPB][NSUB][HSTRIDE];   // 9216 B/block

    const int tid  = threadIdx.x;
    const int wave = tid >> 6;
    const int lane = tid & 63;
    const int sub  = lane >> 3;                // 0..7

    // zero this wave's sub-hists: 576 ints = 144 int4 / 64 lanes
    {
        int4* z = reinterpret_cast<int4*>(&hist[wave][0][0]);
        const int4 zero = make_int4(0, 0, 0, 0);
#pragma unroll
        for (int i = 0; i < 3; ++i) {
            const int idx = lane + i * 64;
            if (idx < (NSUB * HSTRIDE) / 4) z[idx] = zero;
        }
    }

    const int gid = blockIdx.x * WPB + wave;   // 0..6003
    const int b   = gid / NOUT;
    const int w   = gid - b * NOUT;
    const int* __restrict__ row = lbl + b * T;
    const int s = w * HOP - PAD;

    // wave-local ordering: zeros drained before atomics (no block barrier needed)
    asm volatile("s_waitcnt lgkmcnt(0)" ::: "memory");

    int* hsub = &hist[wave][sub][0];
    if (s >= 0 && s + FFT <= T) {
        // fast path (1493/1501 windows): no reflection
        const int4* p = reinterpret_cast<const int4*>(row + s);
#pragma unroll
        for (int k = 0; k < 4; ++k) {
            const int4 v = p[k * 64 + lane];   // 1 KiB/instr, coalesced
            atomicAdd(&hsub[v.x], 1);
            atomicAdd(&hsub[v.y], 1);
            atomicAdd(&hsub[v.z], 1);
            atomicAdd(&hsub[v.w], 1);
        }
    } else {
        // boundary windows (8/1501): reflect-pad indexing, scalar
        auto refl = [&](int j) {
            j = (j < 0) ? -j : j;                 // left reflect (no edge repeat)
            j = (j >= T) ? (2 * (T - 1) - j) : j; // right reflect
            return j;
        };
#pragma unroll
        for (int k = 0; k < 16; ++k) {
            const int lab = row[refl(s + k * 64 + lane)];
            atomicAdd(&hsub[lab], 1);
        }
    }

    // wave-local ordering: all atomics done before merge reads
    asm volatile("s_waitcnt lgkmcnt(0)" ::: "memory");

    // counts: label = lane (0..63); labels 64..71 handled on lanes 0..7.
    // merge reads addr = s*72 + lane -> banks lane-distinct mod 32 (2-way, free)
    int c0 = 0;
#pragma unroll
    for (int s8 = 0; s8 < NSUB; ++s8)
        c0 += hist[wave][s8][lane];
    int k0 = (c0 << 7) | (NUM_LABELS - 1 - lane);

    int k1 = 0;                                // cnt=0,lab=71 -> key 0, never wins
    if (lane < NUM_LABELS - 64) {
        const int l2 = 64 + lane;
        int c1 = 0;
#pragma unroll
        for (int s8 = 0; s8 < NSUB; ++s8)
            c1 += hist[wave][s8][l2];
        k1 = (c1 << 7) | (NUM_LABELS - 1 - l2);
    }

    int k = max(k0, k1);
#pragma unroll
    for (int off = 32; off; off >>= 1)
        k = max(k, __shfl_xor(k, off, 64));
    if (lane == 0)
        out[b * NOUT + w] = NUM_LABELS - 1 - (k & 127);
}

extern "C" void kernel_launch(void* const* d_in, const int* in_sizes, int n_in,
                              void* d_out, int out_size, void* d_ws, size_t ws_size,
                              hipStream_t stream) {
    const int* lbl = (const int*)d_in[0];
    // d_in[1] is the frozen all-ones conv weight: conv == windowed count, ignore.
    int* out = (int*)d_out;

    static_assert(WPB * ((BATCH * NOUT) / WPB) == BATCH * NOUT, "exact wave tiling");
    dim3 grid((BATCH * NOUT) / WPB);           // 1501 blocks, 4 waves each
    label_window_argmax<<<grid, 256, 0, stream>>>(lbl, out);
}